// Round 16
// baseline (151.453 us; speedup 1.0000x reference)
//
#include <hip/hip_runtime.h>
#include <math.h>

#define HD 256
#define SEQ 4096
#define NR 16384
#define NHEADS 4
#define EPSV 1e-5f
#define LDP2 36   // padded LDS row stride for 32-wide K subtiles (<=2-way banks)
#define ZLDP 264  // padded LDS row stride for 256-wide row tiles
#define SROWS 32  // rows per block
#define SHALO 15  // 7 below + 8 above
#define SLDP 264  // halo-tile LDS row stride

typedef __attribute__((ext_vector_type(8))) short bf16x8;
typedef __attribute__((ext_vector_type(4))) float f32x4;

__device__ inline short f2bf(float f) {
    unsigned u = __float_as_uint(f);
    u += 0x7FFF + ((u >> 16) & 1);     // round-to-nearest-even
    return (short)(u >> 16);
}
__device__ inline float bf2f(short s) {
    return __uint_as_float(((unsigned)(unsigned short)s) << 16);
}

// Load one [256 x 32] weight subtile into registers (4 x bf16x8 per thread).
__device__ inline void wload(const short* __restrict__ src, int src_stride,
                             int k0, bf16x8 wreg[4])
{
    int t = threadIdx.x;
#pragma unroll
    for (int c = 0; c < 4; ++c) {
        int idx = c * 256 + t;
        int r = idx >> 2, kg = idx & 3;
        wreg[c] = *(const bf16x8*)(src + (size_t)r * src_stride + k0 + kg * 8);
    }
}
// Write the registers to a padded [256][LDP2] LDS buffer.
__device__ inline void wstore(short* lds, bf16x8 wreg[4])
{
    int t = threadIdx.x;
#pragma unroll
    for (int c = 0; c < 4; ++c) {
        int idx = c * 256 + t;
        int r = idx >> 2, kg = idx & 3;
        *(bf16x8*)(lds + r * LDP2 + kg * 8) = wreg[c];
    }
}

// ---------------------------------------------------------------------------
// Merged prep + stencil (unchanged from round 15). grid (512, 5).
// ---------------------------------------------------------------------------
__global__ __launch_bounds__(256) void prep_stencil(
    const float* __restrict__ x,
    const float* __restrict__ Wc, const float* __restrict__ Wa,
    const float* __restrict__ Wg, const float* __restrict__ Wp,
    short* __restrict__ xb, short* __restrict__ y,
    short* __restrict__ WcT, short* __restrict__ WaT,
    short* __restrict__ WgT, short* __restrict__ WpT)
{
    __shared__ __align__(16) char smem[(SROWS + SHALO) * SLDP * 2];
    int task = blockIdx.y;
    int bx = blockIdx.x;
    int t = threadIdx.x;

    if (task == 0) {                   // stencil + cast
        short* lH = (short*)smem;
        int t0 = bx * SROWS;
        int batch_base = t0 & ~(SEQ - 1);
        for (int i = t; i < (SROWS + SHALO) * 64; i += 256) {
            int r = i >> 6, c4 = (i & 63) * 4;
            int grow = t0 - 7 + r;
            short4 o4 = {0, 0, 0, 0};
            if (grow >= batch_base && grow < batch_base + SEQ) {
                float4 v = *(const float4*)(x + (size_t)grow * HD + c4);
                o4.x = f2bf(v.x); o4.y = f2bf(v.y); o4.z = f2bf(v.z); o4.w = f2bf(v.w);
            }
            *(short4*)(lH + r * SLDP + c4) = o4;
        }
        __syncthreads();
        for (int i = t; i < SROWS * 64; i += 256) {
            int r = i >> 6, c4 = (i & 63) * 4;
            *(short4*)(xb + (size_t)(t0 + r) * HD + c4) =
                *(const short4*)(lH + (r + 7) * SLDP + c4);
        }
        int wv = t >> 6, lane = t & 63;
        int c0 = lane * 4;
        for (int rr = wv; rr < SROWS; rr += 4) {
            float a0 = 0.f, a1 = 0.f, a2 = 0.f, a3 = 0.f;
#pragma unroll
            for (int i = 0; i < 15; ++i) {
                int d = (i < 7) ? (i - 7) : (i - 6);   // -7..-1, 1..8
                float wd = 1.f / (1.f + (float)((d < 0) ? -d : d));
                short4 s4 = *(const short4*)(lH + (rr + 7 + d) * SLDP + c0);
                a0 += wd * bf2f(s4.x); a1 += wd * bf2f(s4.y);
                a2 += wd * bf2f(s4.z); a3 += wd * bf2f(s4.w);
            }
            short4 o;
            o.x = f2bf(a0); o.y = f2bf(a1); o.z = f2bf(a2); o.w = f2bf(a3);
            *(short4*)(y + (size_t)(t0 + rr) * HD + c0) = o;
        }
        return;
    }
    // tasks 1-4: W^T via LDS tile (64x64)
    float (*lds)[65] = (float (*)[65])smem;
    const float* W; short* Wt; int K;
    if (task == 1)      { W = Wc; Wt = WcT; K = 256; }
    else if (task == 2) { W = Wa; Wt = WaT; K = 256; }
    else if (task == 3) { W = Wg; Wt = WgT; K = 512; }
    else                { W = Wp; Wt = WpT; K = 256; }
    int ntiles = (K >> 6) * 4;
    if (bx >= ntiles) return;
    int k0 = (bx >> 2) * 64, n0 = (bx & 3) * 64;
    int ty = t >> 6, tx = t & 63;
#pragma unroll
    for (int s = 0; s < 16; ++s) {
        int r = s * 4 + ty;
        lds[r][tx] = W[(size_t)(k0 + r) * 256 + n0 + tx];
    }
    __syncthreads();
#pragma unroll
    for (int s = 0; s < 16; ++s) {
        int rn = s * 4 + ty;
        Wt[(size_t)(n0 + rn) * K + k0 + tx] = f2bf(lds[tx][rn]);
    }
}

// ---------------------------------------------------------------------------
// Fused middle: block owns 32 rows (grid 512).
//  y staged once into lZ. Each GEMM pass = 8 pipelined BK=32 subtiles,
//  double-buffered weights, issue-early/write-late, 1 barrier/iter.
// LDS: lB pair 36.9K | lZ 16.9K | red 0.5K = 54.3K -> 3 blocks/CU
// ---------------------------------------------------------------------------
__global__ __launch_bounds__(256, 3) void gemm_fused(
    const short* __restrict__ y, const short* __restrict__ WcT,
    const short* __restrict__ xb, const float* __restrict__ bc,
    const short* __restrict__ WaT,
    const float* __restrict__ lng, const float* __restrict__ lnb,
    const float* __restrict__ a_src, const float* __restrict__ a_tgt,
    short* __restrict__ hb, float* __restrict__ es, float* __restrict__ et)
{
    __shared__ __align__(16) short lBp[2][256 * LDP2];   // 2 x 18432B
    __shared__ __align__(16) short lZ[32 * ZLDP];        // y, then LN(z)
    __shared__ float red_s[64], red_q[64];
    int t = threadIdx.x;
    int m0 = blockIdx.x * SROWS;
    int lane = t & 63, wid = t >> 6;
    int wm = wid & 1, wn = wid >> 1;
    int lm = lane & 15, lk = (lane >> 4) * 8;
    int rbase = (lane >> 4) * 4;

    // stage full y tile (32 x 256) into lZ once (coalesced)
#pragma unroll
    for (int c = 0; c < 4; ++c) {
        int idx = c * 256 + t;
        int r = idx >> 5, kg = idx & 31;
        *(bf16x8*)(lZ + r * ZLDP + kg * 8) =
            *(const bf16x8*)(y + (size_t)(m0 + r) * HD + kg * 8);
    }

    // ---- Phase 1: z = y@Wc (pipelined) ----
    f32x4 acc[8] = {};
    {
        bf16x8 w0[4];
        wload(WcT, HD, 0, w0);
        wstore(lBp[0], w0);
    }
    __syncthreads();   // y in lZ + first weight subtile visible
    for (int kt = 0; kt < 8; ++kt) {
        const short* cur = lBp[kt & 1];
        short* nxt = (short*)lBp[(kt & 1) ^ 1];
        bf16x8 wreg[4];
        if (kt < 7) wload(WcT, HD, (kt + 1) * 32, wreg);   // issue early
        bf16x8 a = *(const bf16x8*)(lZ + (wm * 16 + lm) * ZLDP + kt * 32 + lk);
#pragma unroll
        for (int j = 0; j < 8; ++j) {
            bf16x8 b = *(const bf16x8*)(cur + (wn * 128 + j * 16 + lm) * LDP2 + lk);
            acc[j] = __builtin_amdgcn_mfma_f32_16x16x32_bf16(a, b, acc[j], 0, 0, 0);
        }
        if (kt < 7) wstore(nxt, wreg);                     // write late
        __syncthreads();
    }
    float zv[8][4];
    float s4r[4] = {}, q4r[4] = {};
#pragma unroll
    for (int j = 0; j < 8; ++j)
#pragma unroll
        for (int r = 0; r < 4; ++r) {
            int n = wn * 128 + j * 16 + lm;
            int row = m0 + wm * 16 + rbase + r;
            float z = acc[j][r] + bc[n] + bf2f(xb[(size_t)row * HD + n]);
            zv[j][r] = z; s4r[r] += z; q4r[r] += z * z;
        }
#pragma unroll
    for (int r = 0; r < 4; ++r)
#pragma unroll
        for (int o = 1; o < 16; o <<= 1) {
            s4r[r] += __shfl_xor(s4r[r], o, 64);
            q4r[r] += __shfl_xor(q4r[r], o, 64);
        }
    if (lm == 0)
#pragma unroll
        for (int r = 0; r < 4; ++r) {
            red_s[wn * 32 + wm * 16 + rbase + r] = s4r[r];
            red_q[wn * 32 + wm * 16 + rbase + r] = q4r[r];
        }
    __syncthreads();   // stats ready AND all phase-1 lZ reads done
    float mu[4], inv[4];
#pragma unroll
    for (int r = 0; r < 4; ++r) {
        int rowl = wm * 16 + rbase + r;
        float S = red_s[rowl] + red_s[32 + rowl];
        float Q = red_q[rowl] + red_q[32 + rowl];
        mu[r] = S * (1.f / HD);
        inv[r] = rsqrtf(Q * (1.f / HD) - mu[r] * mu[r] + EPSV);
    }
#pragma unroll
    for (int j = 0; j < 8; ++j)
#pragma unroll
        for (int r = 0; r < 4; ++r) {
            int n = wn * 128 + j * 16 + lm;
            int rowl = wm * 16 + rbase + r;
            lZ[rowl * ZLDP + n] = f2bf((zv[j][r] - mu[r]) * inv[r] * lng[n] + lnb[n]);
        }
    {   // prefetch Wa subtile 0 (overlaps LN VALU)
        bf16x8 w0[4];
        wload(WaT, HD, 0, w0);
        wstore((short*)lBp[0], w0);
    }
    __syncthreads();   // LN(z) + Wa tile0 visible

    // ---- Phase 2: h = LN(z) @ Wa (pipelined) ----
    f32x4 acc2[8] = {};
    for (int kt = 0; kt < 8; ++kt) {
        const short* cur = lBp[kt & 1];
        short* nxt = (short*)lBp[(kt & 1) ^ 1];
        bf16x8 wreg[4];
        if (kt < 7) wload(WaT, HD, (kt + 1) * 32, wreg);
        bf16x8 a = *(const bf16x8*)(lZ + (wm * 16 + lm) * ZLDP + kt * 32 + lk);
#pragma unroll
        for (int j = 0; j < 8; ++j) {
            bf16x8 b = *(const bf16x8*)(cur + (wn * 128 + j * 16 + lm) * LDP2 + lk);
            acc2[j] = __builtin_amdgcn_mfma_f32_16x16x32_bf16(a, b, acc2[j], 0, 0, 0);
        }
        if (kt < 7) wstore(nxt, wreg);
        __syncthreads();
    }
    float esA[4] = {}, etA[4] = {}, esB[4] = {}, etB[4] = {};
#pragma unroll
    for (int j = 0; j < 8; ++j) {
        int n = wn * 128 + j * 16 + lm;
        float as = a_src[n], at = a_tgt[n];
#pragma unroll
        for (int r = 0; r < 4; ++r) {
            int row = m0 + wm * 16 + rbase + r;
            hb[(size_t)row * HD + n] = f2bf(acc2[j][r]);
            if (j < 4) { esA[r] += acc2[j][r] * as; etA[r] += acc2[j][r] * at; }
            else       { esB[r] += acc2[j][r] * as; etB[r] += acc2[j][r] * at; }
        }
    }
#pragma unroll
    for (int r = 0; r < 4; ++r) {
#pragma unroll
        for (int o = 1; o < 16; o <<= 1) {
            esA[r] += __shfl_xor(esA[r], o, 64);
            etA[r] += __shfl_xor(etA[r], o, 64);
            esB[r] += __shfl_xor(esB[r], o, 64);
            etB[r] += __shfl_xor(etB[r], o, 64);
        }
        if (lm == 0) {
            int row = m0 + wm * 16 + rbase + r;
            es[row * NHEADS + wn * 2 + 0] = esA[r];
            et[row * NHEADS + wn * 2 + 0] = etA[r];
            es[row * NHEADS + wn * 2 + 1] = esB[r];
            et[row * NHEADS + wn * 2 + 1] = etB[r];
        }
    }
}

// ---------------------------------------------------------------------------
// Fused tail: block owns 32 rows.
//  Phase A: attn + LN -> gs2 in lZ (lH halo + lX staged)
//  3 pipelined GEMM passes (Wg_top, Wg_bot, Wp), BK=32 double-buffered.
// LDS: union(lH 24.8K, lB pair 36.9K) + lZ 16.9K + lX 16.9K = 70.7K
// ---------------------------------------------------------------------------
#define AF_LZ_OFF 36864
#define AF_LX_OFF (36864 + 32 * ZLDP * 2)

__global__ __launch_bounds__(256, 4) void attn_final(
    const short* __restrict__ hb, const float* __restrict__ es,
    const float* __restrict__ et, const short* __restrict__ xb,
    const float* __restrict__ ba, const float* __restrict__ lng,
    const float* __restrict__ lnb,
    const short* __restrict__ WgT, const float* __restrict__ bg,
    const short* __restrict__ WpT, const float* __restrict__ bp,
    float* __restrict__ out)
{
    __shared__ __align__(16) char smem[36864 + 2 * 32 * ZLDP * 2];
    short* lH  = (short*)smem;                 // 47 x SLDP during attn
    short* lB0 = (short*)smem;                 // 256 x LDP2 (passes)
    short* lB1 = (short*)(smem + 256 * LDP2 * 2);
    short* lZ  = (short*)(smem + AF_LZ_OFF);   // gs2, 32 x ZLDP
    short* lX  = (short*)(smem + AF_LX_OFF);   // xb,  32 x ZLDP

    int t = threadIdx.x;
    int t0 = blockIdx.x * SROWS;
    int batch_base = t0 & ~(SEQ - 1);

    // stage h halo tile + xb own rows
    for (int i = t; i < (SROWS + SHALO) * 64; i += 256) {
        int r = i >> 6, c4 = (i & 63) * 4;
        int grow = t0 - 7 + r;
        short4 v = {0, 0, 0, 0};
        if (grow >= batch_base && grow < batch_base + SEQ)
            v = *(const short4*)(hb + (size_t)grow * HD + c4);
        *(short4*)(lH + r * SLDP + c4) = v;
    }
    for (int i = t; i < SROWS * 64; i += 256) {
        int r = i >> 6, c4 = (i & 63) * 4;
        *(short4*)(lX + r * ZLDP + c4) = *(const short4*)(xb + (size_t)(t0 + r) * HD + c4);
    }
    __syncthreads();

    // ---- Phase A: attn + LN -> lZ ----
    int wv = t >> 6, lane = t & 63;
    int tap = lane >> 2, hh = lane & 3;
    int hd = lane >> 4;
    int c0 = lane * 4;
    for (int rr = wv; rr < SROWS; rr += 4) {
        int trow = t0 + rr;
        int p = trow & (SEQ - 1);
        float lg = -1e30f, wd = 0.f;
        bool okk = false;
        if (tap < 15) {
            int d = (tap < 7) ? (tap - 7) : (tap - 6);
            int qp = p + d;
            okk = (qp >= 0) && (qp < SEQ);
            if (okk) {
                float l = es[(trow + d) * NHEADS + hh] + et[trow * NHEADS + hh];
                lg = (l > 0.f) ? l : 0.2f * l;
            }
            wd = 1.f / (1.f + (float)((d < 0) ? -d : d));
        }
        float m = lg;
#pragma unroll
        for (int o = 4; o < 64; o <<= 1) m = fmaxf(m, __shfl_xor(m, o, 64));
        float un = okk ? __expf(lg - m) * wd : 0.f;
        float den = un;
#pragma unroll
        for (int o = 4; o < 64; o <<= 1) den += __shfl_xor(den, o, 64);
        float alpha_l = un / (den + 1e-9f);

        float al[15];
#pragma unroll
        for (int i = 0; i < 15; ++i) al[i] = __shfl(alpha_l, i * 4 + hd, 64);

        float a0 = 0.f, a1 = 0.f, a2 = 0.f, a3 = 0.f;
#pragma unroll
        for (int i = 0; i < 15; ++i) {
            int d = (i < 7) ? (i - 7) : (i - 6);
            short4 s4 = *(const short4*)(lH + (rr + 7 + d) * SLDP + c0);
            a0 += al[i] * bf2f(s4.x); a1 += al[i] * bf2f(s4.y);
            a2 += al[i] * bf2f(s4.z); a3 += al[i] * bf2f(s4.w);
        }
        short4 xv4 = *(const short4*)(lX + rr * ZLDP + c0);
        float4 bav = *(const float4*)(ba + c0);
        float v0 = a0 + bav.x + bf2f(xv4.x), v1 = a1 + bav.y + bf2f(xv4.y);
        float v2 = a2 + bav.z + bf2f(xv4.z), v3 = a3 + bav.w + bf2f(xv4.w);
        float s = v0 + v1 + v2 + v3;
        float q = v0 * v0 + v1 * v1 + v2 * v2 + v3 * v3;
#pragma unroll
        for (int o = 1; o < 64; o <<= 1) { s += __shfl_xor(s, o, 64); q += __shfl_xor(q, o, 64); }
        float mu = s * (1.f / HD);
        float var = q * (1.f / HD) - mu * mu;
        float inv = rsqrtf(var + EPSV);
        float4 gv = *(const float4*)(lng + c0);
        float4 bv = *(const float4*)(lnb + c0);
        short4 o4;
        o4.x = f2bf((v0 - mu) * inv * gv.x + bv.x);
        o4.y = f2bf((v1 - mu) * inv * gv.y + bv.y);
        o4.z = f2bf((v2 - mu) * inv * gv.z + bv.z);
        o4.w = f2bf((v3 - mu) * inv * gv.w + bv.w);
        *(short4*)(lZ + rr * ZLDP + c0) = o4;
    }
    __syncthreads();   // all lH reads done before lB overwrite; lZ ready

    // ---- 3 pipelined GEMM passes ----
    int wid = t >> 6;
    int wm = wid & 1, wn = wid >> 1;
    int lm = lane & 15, lk = (lane >> 4) * 8;
    int rbase = (lane >> 4) * 4;
    f32x4 accg[8] = {}, accp[8] = {};
    short* lBp[2] = {lB0, lB1};

    // pass 1: accg = xb @ Wg_top (A from lX)
    {
        bf16x8 w0[4];
        wload(WgT, 512, 0, w0); wstore(lB0, w0);
    }
    __syncthreads();
    for (int kt = 0; kt < 8; ++kt) {
        const short* cur = lBp[kt & 1];
        short* nxt = lBp[(kt & 1) ^ 1];
        bf16x8 wreg[4];
        if (kt < 7) wload(WgT, 512, (kt + 1) * 32, wreg);
        bf16x8 a = *(const bf16x8*)(lX + (wm * 16 + lm) * ZLDP + kt * 32 + lk);
#pragma unroll
        for (int j = 0; j < 8; ++j) {
            bf16x8 b = *(const bf16x8*)(cur + (wn * 128 + j * 16 + lm) * LDP2 + lk);
            accg[j] = __builtin_amdgcn_mfma_f32_16x16x32_bf16(a, b, accg[j], 0, 0, 0);
        }
        if (kt < 7) wstore(nxt, wreg);
        __syncthreads();
    }
    // pass 2: accg += gs2 @ Wg_bot
    {
        bf16x8 w0[4];
        wload(WgT, 512, 256, w0); wstore(lB0, w0);
    }
    __syncthreads();
    for (int kt = 0; kt < 8; ++kt) {
        const short* cur = lBp[kt & 1];
        short* nxt = lBp[(kt & 1) ^ 1];
        bf16x8 wreg[4];
        if (kt < 7) wload(WgT, 512, 256 + (kt + 1) * 32, wreg);
        bf16x8 a = *(const bf16x8*)(lZ + (wm * 16 + lm) * ZLDP + kt * 32 + lk);
#pragma unroll
        for (int j = 0; j < 8; ++j) {
            bf16x8 b = *(const bf16x8*)(cur + (wn * 128 + j * 16 + lm) * LDP2 + lk);
            accg[j] = __builtin_amdgcn_mfma_f32_16x16x32_bf16(a, b, accg[j], 0, 0, 0);
        }
        if (kt < 7) wstore(nxt, wreg);
        __syncthreads();
    }
    // pass 3: accp = gs2 @ Wp
    {
        bf16x8 w0[4];
        wload(WpT, HD, 0, w0); wstore(lB0, w0);
    }
    __syncthreads();
    for (int kt = 0; kt < 8; ++kt) {
        const short* cur = lBp[kt & 1];
        short* nxt = lBp[(kt & 1) ^ 1];
        bf16x8 wreg[4];
        if (kt < 7) wload(WpT, HD, (kt + 1) * 32, wreg);
        bf16x8 a = *(const bf16x8*)(lZ + (wm * 16 + lm) * ZLDP + kt * 32 + lk);
#pragma unroll
        for (int j = 0; j < 8; ++j) {
            bf16x8 b = *(const bf16x8*)(cur + (wn * 128 + j * 16 + lm) * LDP2 + lk);
            accp[j] = __builtin_amdgcn_mfma_f32_16x16x32_bf16(a, b, accp[j], 0, 0, 0);
        }
        if (kt < 7) wstore(nxt, wreg);
        __syncthreads();
    }
    // epilogue
#pragma unroll
    for (int j = 0; j < 8; ++j)
#pragma unroll
        for (int r = 0; r < 4; ++r) {
            int n = wn * 128 + j * 16 + lm;
            int rowl = wm * 16 + rbase + r;
            size_t m = (size_t)(t0 + rowl);
            float gate = 1.f / (1.f + __expf(-(accg[j][r] + bg[n])));
            float pv = accp[j][r] + bp[n];
            out[m * HD + n] = bf2f(lX[rowl * ZLDP + n]) + gate * pv;
        }
}

// ---------------------------------------------------------------------------
extern "C" void kernel_launch(void* const* d_in, const int* in_sizes, int n_in,
                              void* d_out, int out_size, void* d_ws, size_t ws_size,
                              hipStream_t stream)
{
    const float* x     = (const float*)d_in[0];
    const float* Wc    = (const float*)d_in[1];
    const float* bc    = (const float*)d_in[2];
    const float* Wa    = (const float*)d_in[3];
    const float* a_src = (const float*)d_in[4];
    const float* a_tgt = (const float*)d_in[5];
    const float* ba    = (const float*)d_in[6];
    const float* ln_g  = (const float*)d_in[7];
    const float* ln_b  = (const float*)d_in[8];
    const float* Wg    = (const float*)d_in[9];
    const float* bg    = (const float*)d_in[10];
    const float* Wp    = (const float*)d_in[11];
    const float* bp    = (const float*)d_in[12];

    float* out = (float*)d_out;      // written only by attn_final

    char* w = (char*)d_ws;
    short* y   = (short*)w;   w += (size_t)NR * HD * 2;   // stencil(x) bf16
    short* xb  = (short*)w;   w += (size_t)NR * HD * 2;   // bf16 x
    short* hb  = (short*)w;   w += (size_t)NR * HD * 2;   // h bf16
    float* es  = (float*)w;   w += (size_t)NR * NHEADS * 4;
    float* et  = (float*)w;   w += (size_t)NR * NHEADS * 4;
    short* WcT = (short*)w;   w += 256 * 256 * 2;
    short* WaT = (short*)w;   w += 256 * 256 * 2;
    short* WpT = (short*)w;   w += 256 * 256 * 2;
    short* WgT = (short*)w;   w += 512 * 256 * 2;

    // 0) merged: stencil+cast / weights^T
    prep_stencil<<<dim3(NR / SROWS, 5), 256, 0, stream>>>(
        x, Wc, Wa, Wg, Wp, xb, y, WcT, WaT, WgT, WpT);
    // 1) fused: z=y@Wc+bc+xb -> LN -> h=LN(z)@Wa -> es/et   (z stays in LDS)
    gemm_fused<<<NR / SROWS, 256, 0, stream>>>(y, WcT, xb, bc, WaT, ln_g, ln_b,
                                               a_src, a_tgt, hb, es, et);
    // 2) fused: gs2 = LN(attn(h)+ba+xb) in LDS -> out = xb + gate*(gs2@Wp+bp)
    attn_final<<<NR / SROWS, 256, 0, stream>>>(hb, es, et, xb, ba, ln_g, ln_b,
                                               WgT, bg, WpT, bp, out);
}

// Round 17
// 66.382 us; speedup vs baseline: 2.2815x; 2.2815x over previous
//
#include <hip/hip_runtime.h>
#include <math.h>

#define HD 256
#define SEQ 4096
#define NR 16384
#define NHEADS 4
#define EPSV 1e-5f
#define LDP 72    // padded LDS row stride for GEMM K-tiles
#define ZLDP 264  // padded LDS row stride for 256-wide row tiles
#define SROWS 32  // rows per block
#define SHALO 15  // 7 below + 8 above
#define SLDP 264  // halo-tile LDS row stride

typedef __attribute__((ext_vector_type(8))) short bf16x8;
typedef __attribute__((ext_vector_type(4))) float f32x4;

__device__ inline short f2bf(float f) {
    unsigned u = __float_as_uint(f);
    u += 0x7FFF + ((u >> 16) & 1);     // round-to-nearest-even
    return (short)(u >> 16);
}
__device__ inline float bf2f(short s) {
    return __uint_as_float(((unsigned)(unsigned short)s) << 16);
}

// Stage a [rows x 64] bf16 tile into padded LDS. Coalesced 16B chunks.
__device__ inline void stage_tile(const short* __restrict__ src, int src_stride,
                                  int row0, int k0, short* lds, int rows)
{
    int t = threadIdx.x;
    int nchunk = rows >> 5;
#pragma unroll
    for (int c = 0; c < 8; ++c) {
        if (c >= nchunk) break;
        int idx = c * 256 + t;
        int r = idx >> 3, kg = idx & 7;
        bf16x8 v = *(const bf16x8*)(src + (size_t)(row0 + r) * src_stride + k0 + kg * 8);
        *(bf16x8*)(lds + r * LDP + kg * 8) = v;
    }
}

// ---------------------------------------------------------------------------
// Merged prep + stencil. grid (512, 5):
//  task 0: stencil+cast: xb = bf16(x), y = 15-tap stencil(x)
//  tasks 1-4: weight transpose+cast (Wc/Wa/Wg/Wp)
// ---------------------------------------------------------------------------
__global__ __launch_bounds__(256) void prep_stencil(
    const float* __restrict__ x,
    const float* __restrict__ Wc, const float* __restrict__ Wa,
    const float* __restrict__ Wg, const float* __restrict__ Wp,
    short* __restrict__ xb, short* __restrict__ y,
    short* __restrict__ WcT, short* __restrict__ WaT,
    short* __restrict__ WgT, short* __restrict__ WpT)
{
    __shared__ __align__(16) char smem[(SROWS + SHALO) * SLDP * 2];
    int task = blockIdx.y;
    int bx = blockIdx.x;
    int t = threadIdx.x;

    if (task == 0) {                   // stencil + cast
        short* lH = (short*)smem;
        int t0 = bx * SROWS;
        int batch_base = t0 & ~(SEQ - 1);
        for (int i = t; i < (SROWS + SHALO) * 64; i += 256) {
            int r = i >> 6, c4 = (i & 63) * 4;
            int grow = t0 - 7 + r;
            short4 o4 = {0, 0, 0, 0};
            if (grow >= batch_base && grow < batch_base + SEQ) {
                float4 v = *(const float4*)(x + (size_t)grow * HD + c4);
                o4.x = f2bf(v.x); o4.y = f2bf(v.y); o4.z = f2bf(v.z); o4.w = f2bf(v.w);
            }
            *(short4*)(lH + r * SLDP + c4) = o4;
        }
        __syncthreads();
        for (int i = t; i < SROWS * 64; i += 256) {
            int r = i >> 6, c4 = (i & 63) * 4;
            *(short4*)(xb + (size_t)(t0 + r) * HD + c4) =
                *(const short4*)(lH + (r + 7) * SLDP + c4);
        }
        int wv = t >> 6, lane = t & 63;
        int c0 = lane * 4;
        for (int rr = wv; rr < SROWS; rr += 4) {
            float a0 = 0.f, a1 = 0.f, a2 = 0.f, a3 = 0.f;
#pragma unroll
            for (int i = 0; i < 15; ++i) {
                int d = (i < 7) ? (i - 7) : (i - 6);   // -7..-1, 1..8
                float wd = 1.f / (1.f + (float)((d < 0) ? -d : d));
                short4 s4 = *(const short4*)(lH + (rr + 7 + d) * SLDP + c0);
                a0 += wd * bf2f(s4.x); a1 += wd * bf2f(s4.y);
                a2 += wd * bf2f(s4.z); a3 += wd * bf2f(s4.w);
            }
            short4 o;
            o.x = f2bf(a0); o.y = f2bf(a1); o.z = f2bf(a2); o.w = f2bf(a3);
            *(short4*)(y + (size_t)(t0 + rr) * HD + c0) = o;
        }
        return;
    }
    // tasks 1-4: W^T via LDS tile (64x64)
    float (*lds)[65] = (float (*)[65])smem;
    const float* W; short* Wt; int K;
    if (task == 1)      { W = Wc; Wt = WcT; K = 256; }
    else if (task == 2) { W = Wa; Wt = WaT; K = 256; }
    else if (task == 3) { W = Wg; Wt = WgT; K = 512; }
    else                { W = Wp; Wt = WpT; K = 256; }
    int ntiles = (K >> 6) * 4;
    if (bx >= ntiles) return;
    int k0 = (bx >> 2) * 64, n0 = (bx & 3) * 64;
    int ty = t >> 6, tx = t & 63;
#pragma unroll
    for (int s = 0; s < 16; ++s) {
        int r = s * 4 + ty;
        lds[r][tx] = W[(size_t)(k0 + r) * 256 + n0 + tx];
    }
    __syncthreads();
#pragma unroll
    for (int s = 0; s < 16; ++s) {
        int rn = s * 4 + ty;
        Wt[(size_t)(n0 + rn) * K + k0 + tx] = f2bf(lds[tx][rn]);
    }
}

// ---------------------------------------------------------------------------
// Fused middle: block owns 32 FULL rows.
//  Phase 1: z = y@Wc + bc + xb (regs) -> row LN stats (local) -> LN(z) to LDS
//  Phase 2: h = LN(z) @ Wa (A from LDS) -> global; es/et dots (wave-local)
// Waves: 2(M) x 2(N-half of 128). No atomics, z never hits global.
// ---------------------------------------------------------------------------
__global__ __launch_bounds__(256) void gemm_fused(
    const short* __restrict__ y, const short* __restrict__ WcT,
    const short* __restrict__ xb, const float* __restrict__ bc,
    const short* __restrict__ WaT,
    const float* __restrict__ lng, const float* __restrict__ lnb,
    const float* __restrict__ a_src, const float* __restrict__ a_tgt,
    short* __restrict__ hb, float* __restrict__ es, float* __restrict__ et)
{
    __shared__ __align__(16) short lA[32 * LDP];
    __shared__ __align__(16) short lB[256 * LDP];
    __shared__ __align__(16) short lZ[32 * ZLDP];
    __shared__ float red_s[2][32], red_q[2][32];
    int t = threadIdx.x;
    int lane = t & 63, wid = t >> 6;
    int wm = wid & 1, wn = wid >> 1;
    int m0 = blockIdx.x * 32;
    int lm = lane & 15, lk = (lane >> 4) * 8;
    int rbase = (lane >> 4) * 4;

    // ---- Phase 1: z = y@Wc ----
    f32x4 acc[8] = {};
    for (int kt = 0; kt < 4; ++kt) {
        __syncthreads();
        {   // stage y tile 32x64
            int r = t >> 3, kg = t & 7;
            *(bf16x8*)(lA + r * LDP + kg * 8) =
                *(const bf16x8*)(y + (size_t)(m0 + r) * HD + kt * 64 + kg * 8);
        }
        stage_tile(WcT, HD, 0, kt * 64, lB, 256);
        __syncthreads();
#pragma unroll
        for (int kk2 = 0; kk2 < 64; kk2 += 32) {
            bf16x8 a = *(const bf16x8*)(lA + (wm * 16 + lm) * LDP + kk2 + lk);
#pragma unroll
            for (int j = 0; j < 8; ++j) {
                bf16x8 b = *(const bf16x8*)(lB + (wn * 128 + j * 16 + lm) * LDP + kk2 + lk);
                acc[j] = __builtin_amdgcn_mfma_f32_16x16x32_bf16(a, b, acc[j], 0, 0, 0);
            }
        }
    }
    float zv[8][4];
    float s4r[4] = {}, q4r[4] = {};
#pragma unroll
    for (int j = 0; j < 8; ++j)
#pragma unroll
        for (int r = 0; r < 4; ++r) {
            int n = wn * 128 + j * 16 + lm;
            int row = m0 + wm * 16 + rbase + r;
            float z = acc[j][r] + bc[n] + bf2f(xb[(size_t)row * HD + n]);
            zv[j][r] = z; s4r[r] += z; q4r[r] += z * z;
        }
#pragma unroll
    for (int r = 0; r < 4; ++r)
#pragma unroll
        for (int o = 1; o < 16; o <<= 1) {
            s4r[r] += __shfl_xor(s4r[r], o, 64);
            q4r[r] += __shfl_xor(q4r[r], o, 64);
        }
    if (lm == 0)
#pragma unroll
        for (int r = 0; r < 4; ++r) {
            red_s[wn][wm * 16 + rbase + r] = s4r[r];
            red_q[wn][wm * 16 + rbase + r] = q4r[r];
        }
    __syncthreads();
    float mu[4], inv[4];
#pragma unroll
    for (int r = 0; r < 4; ++r) {
        int rowl = wm * 16 + rbase + r;
        float S = red_s[0][rowl] + red_s[1][rowl];
        float Q = red_q[0][rowl] + red_q[1][rowl];
        mu[r] = S * (1.f / HD);
        inv[r] = rsqrtf(Q * (1.f / HD) - mu[r] * mu[r] + EPSV);
    }
#pragma unroll
    for (int j = 0; j < 8; ++j)
#pragma unroll
        for (int r = 0; r < 4; ++r) {
            int n = wn * 128 + j * 16 + lm;
            int rowl = wm * 16 + rbase + r;
            lZ[rowl * ZLDP + n] = f2bf((zv[j][r] - mu[r]) * inv[r] * lng[n] + lnb[n]);
        }

    // ---- Phase 2: h = LN(z) @ Wa ----
    f32x4 acc2[8] = {};
    for (int kt = 0; kt < 4; ++kt) {
        __syncthreads();
        stage_tile(WaT, HD, 0, kt * 64, lB, 256);
        __syncthreads();
#pragma unroll
        for (int kk2 = 0; kk2 < 64; kk2 += 32) {
            bf16x8 a = *(const bf16x8*)(lZ + (wm * 16 + lm) * ZLDP + kt * 64 + kk2 + lk);
#pragma unroll
            for (int j = 0; j < 8; ++j) {
                bf16x8 b = *(const bf16x8*)(lB + (wn * 128 + j * 16 + lm) * LDP + kk2 + lk);
                acc2[j] = __builtin_amdgcn_mfma_f32_16x16x32_bf16(a, b, acc2[j], 0, 0, 0);
            }
        }
    }
    float esA[4] = {}, etA[4] = {}, esB[4] = {}, etB[4] = {};
#pragma unroll
    for (int j = 0; j < 8; ++j) {
        int n = wn * 128 + j * 16 + lm;
        float as = a_src[n], at = a_tgt[n];
#pragma unroll
        for (int r = 0; r < 4; ++r) {
            int row = m0 + wm * 16 + rbase + r;
            hb[(size_t)row * HD + n] = f2bf(acc2[j][r]);
            if (j < 4) { esA[r] += acc2[j][r] * as; etA[r] += acc2[j][r] * at; }
            else       { esB[r] += acc2[j][r] * as; etB[r] += acc2[j][r] * at; }
        }
    }
#pragma unroll
    for (int r = 0; r < 4; ++r) {
#pragma unroll
        for (int o = 1; o < 16; o <<= 1) {
            esA[r] += __shfl_xor(esA[r], o, 64);
            etA[r] += __shfl_xor(etA[r], o, 64);
            esB[r] += __shfl_xor(esB[r], o, 64);
            etB[r] += __shfl_xor(etB[r], o, 64);
        }
        if (lm == 0) {
            int row = m0 + wm * 16 + rbase + r;
            es[row * NHEADS + wn * 2 + 0] = esA[r];
            et[row * NHEADS + wn * 2 + 0] = etA[r];
            es[row * NHEADS + wn * 2 + 1] = esB[r];
            et[row * NHEADS + wn * 2 + 1] = etB[r];
        }
    }
}

// ---------------------------------------------------------------------------
// Fused tail: block owns 32 rows.
//  Phase A: attn + LN -> gs2 in LDS (h halo staged; xb staged; never global)
//  Phase B: gate = sigmoid(xb@Wg_top + gs2@Wg_bot + bg)  [2 staged passes]
//  Phase C: p = gs2@Wp + bp; out = xb + gate * p
// LDS: region0 = lH(24.8K) then lB(36.9K); lZ(16.9K); lX(16.9K) = 70.7KB.
// ---------------------------------------------------------------------------
#define AF_LZ_OFF (256 * LDP * 2)
#define AF_LX_OFF (256 * LDP * 2 + 32 * ZLDP * 2)

__global__ __launch_bounds__(256) void attn_final(
    const short* __restrict__ hb, const float* __restrict__ es,
    const float* __restrict__ et, const short* __restrict__ xb,
    const float* __restrict__ ba, const float* __restrict__ lng,
    const float* __restrict__ lnb,
    const short* __restrict__ WgT, const float* __restrict__ bg,
    const short* __restrict__ WpT, const float* __restrict__ bp,
    float* __restrict__ out)
{
    __shared__ __align__(16) char smem[256 * LDP * 2 + 2 * 32 * ZLDP * 2];
    short* lH = (short*)smem;                 // 47 x SLDP during attn
    short* lB = (short*)smem;                 // 256 x LDP during GEMMs
    short* lZ = (short*)(smem + AF_LZ_OFF);   // gs2, 32 x ZLDP
    short* lX = (short*)(smem + AF_LX_OFF);   // xb,  32 x ZLDP

    int t = threadIdx.x;
    int t0 = blockIdx.x * SROWS;
    int batch_base = t0 & ~(SEQ - 1);

    // stage h halo tile + xb own rows
    for (int i = t; i < (SROWS + SHALO) * 64; i += 256) {
        int r = i >> 6, c4 = (i & 63) * 4;
        int grow = t0 - 7 + r;
        short4 v = {0, 0, 0, 0};
        if (grow >= batch_base && grow < batch_base + SEQ)
            v = *(const short4*)(hb + (size_t)grow * HD + c4);
        *(short4*)(lH + r * SLDP + c4) = v;
    }
    for (int i = t; i < SROWS * 64; i += 256) {
        int r = i >> 6, c4 = (i & 63) * 4;
        *(short4*)(lX + r * ZLDP + c4) = *(const short4*)(xb + (size_t)(t0 + r) * HD + c4);
    }
    __syncthreads();

    // ---- Phase A: attn + LN -> lZ ----
    int wv = t >> 6, lane = t & 63;
    int tap = lane >> 2, hh = lane & 3;
    int hd = lane >> 4;
    int c0 = lane * 4;
    for (int rr = wv; rr < SROWS; rr += 4) {
        int trow = t0 + rr;
        int p = trow & (SEQ - 1);
        float lg = -1e30f, wd = 0.f;
        bool okk = false;
        if (tap < 15) {
            int d = (tap < 7) ? (tap - 7) : (tap - 6);
            int qp = p + d;
            okk = (qp >= 0) && (qp < SEQ);
            if (okk) {
                float l = es[(trow + d) * NHEADS + hh] + et[trow * NHEADS + hh];
                lg = (l > 0.f) ? l : 0.2f * l;
            }
            wd = 1.f / (1.f + (float)((d < 0) ? -d : d));
        }
        float m = lg;
#pragma unroll
        for (int o = 4; o < 64; o <<= 1) m = fmaxf(m, __shfl_xor(m, o, 64));
        float un = okk ? __expf(lg - m) * wd : 0.f;
        float den = un;
#pragma unroll
        for (int o = 4; o < 64; o <<= 1) den += __shfl_xor(den, o, 64);
        float alpha_l = un / (den + 1e-9f);

        float al[15];
#pragma unroll
        for (int i = 0; i < 15; ++i) al[i] = __shfl(alpha_l, i * 4 + hd, 64);

        float a0 = 0.f, a1 = 0.f, a2 = 0.f, a3 = 0.f;
#pragma unroll
        for (int i = 0; i < 15; ++i) {
            int d = (i < 7) ? (i - 7) : (i - 6);
            short4 s4 = *(const short4*)(lH + (rr + 7 + d) * SLDP + c0);
            a0 += al[i] * bf2f(s4.x); a1 += al[i] * bf2f(s4.y);
            a2 += al[i] * bf2f(s4.z); a3 += al[i] * bf2f(s4.w);
        }
        short4 xv4 = *(const short4*)(lX + rr * ZLDP + c0);
        float4 bav = *(const float4*)(ba + c0);
        float v0 = a0 + bav.x + bf2f(xv4.x), v1 = a1 + bav.y + bf2f(xv4.y);
        float v2 = a2 + bav.z + bf2f(xv4.z), v3 = a3 + bav.w + bf2f(xv4.w);
        float s = v0 + v1 + v2 + v3;
        float q = v0 * v0 + v1 * v1 + v2 * v2 + v3 * v3;
#pragma unroll
        for (int o = 1; o < 64; o <<= 1) { s += __shfl_xor(s, o, 64); q += __shfl_xor(q, o, 64); }
        float mu = s * (1.f / HD);
        float var = q * (1.f / HD) - mu * mu;
        float inv = rsqrtf(var + EPSV);
        float4 gv = *(const float4*)(lng + c0);
        float4 bv = *(const float4*)(lnb + c0);
        short4 o4;
        o4.x = f2bf((v0 - mu) * inv * gv.x + bv.x);
        o4.y = f2bf((v1 - mu) * inv * gv.y + bv.y);
        o4.z = f2bf((v2 - mu) * inv * gv.z + bv.z);
        o4.w = f2bf((v3 - mu) * inv * gv.w + bv.w);
        *(short4*)(lZ + rr * ZLDP + c0) = o4;
    }

    // ---- Phases B/C: three staged GEMM passes ----
    int wid = t >> 6;
    int wm = wid & 1, wn = wid >> 1;
    int lm = lane & 15, lk = (lane >> 4) * 8;
    int rbase = (lane >> 4) * 4;
    f32x4 accg[8] = {}, accp[8] = {};
    // pass 1: accg += xb @ Wg_top
    for (int kt = 0; kt < 4; ++kt) {
        __syncthreads();
        stage_tile(WgT, 512, 0, kt * 64, lB, 256);
        __syncthreads();
#pragma unroll
        for (int kk2 = 0; kk2 < 64; kk2 += 32) {
            bf16x8 a = *(const bf16x8*)(lX + (wm * 16 + lm) * ZLDP + kt * 64 + kk2 + lk);
#pragma unroll
            for (int j = 0; j < 8; ++j) {
                bf16x8 b = *(const bf16x8*)(lB + (wn * 128 + j * 16 + lm) * LDP + kk2 + lk);
                accg[j] = __builtin_amdgcn_mfma_f32_16x16x32_bf16(a, b, accg[j], 0, 0, 0);
            }
        }
    }
    // pass 2: accg += gs2 @ Wg_bot
    for (int kt = 0; kt < 4; ++kt) {
        __syncthreads();
        stage_tile(WgT, 512, 0, 256 + kt * 64, lB, 256);
        __syncthreads();
#pragma unroll
        for (int kk2 = 0; kk2 < 64; kk2 += 32) {
            bf16x8 a = *(const bf16x8*)(lZ + (wm * 16 + lm) * ZLDP + kt * 64 + kk2 + lk);
#pragma unroll
            for (int j = 0; j < 8; ++j) {
                bf16x8 b = *(const bf16x8*)(lB + (wn * 128 + j * 16 + lm) * LDP + kk2 + lk);
                accg[j] = __builtin_amdgcn_mfma_f32_16x16x32_bf16(a, b, accg[j], 0, 0, 0);
            }
        }
    }
    // pass 3: accp = gs2 @ Wp
    for (int kt = 0; kt < 4; ++kt) {
        __syncthreads();
        stage_tile(WpT, HD, 0, kt * 64, lB, 256);
        __syncthreads();
#pragma unroll
        for (int kk2 = 0; kk2 < 64; kk2 += 32) {
            bf16x8 a = *(const bf16x8*)(lZ + (wm * 16 + lm) * ZLDP + kt * 64 + kk2 + lk);
#pragma unroll
            for (int j = 0; j < 8; ++j) {
                bf16x8 b = *(const bf16x8*)(lB + (wn * 128 + j * 16 + lm) * LDP + kk2 + lk);
                accp[j] = __builtin_amdgcn_mfma_f32_16x16x32_bf16(a, b, accp[j], 0, 0, 0);
            }
        }
    }
    // epilogue
#pragma unroll
    for (int j = 0; j < 8; ++j)
#pragma unroll
        for (int r = 0; r < 4; ++r) {
            int n = wn * 128 + j * 16 + lm;
            int rowl = wm * 16 + rbase + r;
            size_t m = (size_t)(t0 + rowl);
            float gate = 1.f / (1.f + __expf(-(accg[j][r] + bg[n])));
            float pv = accp[j][r] + bp[n];
            out[m * HD + n] = bf2f(lX[rowl * ZLDP + n]) + gate * pv;
        }
}

// ---------------------------------------------------------------------------
extern "C" void kernel_launch(void* const* d_in, const int* in_sizes, int n_in,
                              void* d_out, int out_size, void* d_ws, size_t ws_size,
                              hipStream_t stream)
{
    const float* x     = (const float*)d_in[0];
    const float* Wc    = (const float*)d_in[1];
    const float* bc    = (const float*)d_in[2];
    const float* Wa    = (const float*)d_in[3];
    const float* a_src = (const float*)d_in[4];
    const float* a_tgt = (const float*)d_in[5];
    const float* ba    = (const float*)d_in[6];
    const float* ln_g  = (const float*)d_in[7];
    const float* ln_b  = (const float*)d_in[8];
    const float* Wg    = (const float*)d_in[9];
    const float* bg    = (const float*)d_in[10];
    const float* Wp    = (const float*)d_in[11];
    const float* bp    = (const float*)d_in[12];

    float* out = (float*)d_out;      // written only by attn_final

    char* w = (char*)d_ws;
    short* y   = (short*)w;   w += (size_t)NR * HD * 2;   // stencil(x) bf16
    short* xb  = (short*)w;   w += (size_t)NR * HD * 2;   // bf16 x
    short* hb  = (short*)w;   w += (size_t)NR * HD * 2;   // h bf16
    float* es  = (float*)w;   w += (size_t)NR * NHEADS * 4;
    float* et  = (float*)w;   w += (size_t)NR * NHEADS * 4;
    short* WcT = (short*)w;   w += 256 * 256 * 2;
    short* WaT = (short*)w;   w += 256 * 256 * 2;
    short* WpT = (short*)w;   w += 256 * 256 * 2;
    short* WgT = (short*)w;   w += 512 * 256 * 2;

    // 0) merged: stencil+cast / weights^T
    prep_stencil<<<dim3(NR / SROWS, 5), 256, 0, stream>>>(
        x, Wc, Wa, Wg, Wp, xb, y, WcT, WaT, WgT, WpT);
    // 1) fused: z=y@Wc+bc+xb -> LN -> h=LN(z)@Wa -> es/et   (z stays in LDS)
    gemm_fused<<<NR / SROWS, 256, 0, stream>>>(y, WcT, xb, bc, WaT, ln_g, ln_b,
                                               a_src, a_tgt, hb, es, et);
    // 2) fused: gs2 = LN(attn(h)+ba+xb) in LDS -> out = xb + gate*(gs2@Wp+bp)
    attn_final<<<NR / SROWS, 256, 0, stream>>>(hb, es, et, xb, ba, ln_g, ln_b,
                                               WgT, bg, WpT, bp, out);
}